// Round 1
// 425.262 us; speedup vs baseline: 1.1383x; 1.1383x over previous
//
#include <hip/hip_runtime.h>

#define GRID 64
#define N_VOX (GRID * GRID * GRID)   // 262144
#define NCH 64

// ============================================================================
// Pipeline: hist(+rank) -> bsum -> scan2 -> scanfinal(gstart) ->
//           scatter(no atomics) -> gather(LDS-staged indices)
// ============================================================================

typedef float f32x4 __attribute__((ext_vector_type(4)));
typedef int   i32x4 __attribute__((ext_vector_type(4)));

__device__ __forceinline__ int vox_of(int x, int y, int z) {
    return ((x >> 2) << 12) | ((y >> 2) << 6) | (z >> 2);
}

__device__ __forceinline__ float4 max4(float4 a, float4 b) {
    float4 r;
    r.x = fmaxf(a.x, b.x); r.y = fmaxf(a.y, b.y);
    r.z = fmaxf(a.z, b.z); r.w = fmaxf(a.w, b.w);
    return r;
}

// non-temporal helpers (read-once / write-once data: keep it out of L2)
__device__ __forceinline__ float4 ntload4(const float4* p) {
    f32x4 v = __builtin_nontemporal_load((const f32x4*)p);
    return make_float4(v[0], v[1], v[2], v[3]);
}
__device__ __forceinline__ void ntstore4(float4* p, float4 v) {
    f32x4 t; t[0] = v.x; t[1] = v.y; t[2] = v.z; t[3] = v.w;
    __builtin_nontemporal_store(t, (f32x4*)p);
}
__device__ __forceinline__ int4 ntload_i4(const int4* p) {
    i32x4 v = __builtin_nontemporal_load((const i32x4*)p);
    return make_int4(v[0], v[1], v[2], v[3]);
}

// ---- k1: voxel id + in-voxel rank per point + histogram, 4 pts/thread ---
__global__ void k_hist(const int* __restrict__ verts, int* __restrict__ vox,
                       int* __restrict__ rank, int* __restrict__ counts, int n) {
    int t  = blockIdx.x * blockDim.x + threadIdx.x;
    int p0 = t * 4;
    if (p0 >= n) return;

    if (p0 + 4 <= n) {
        const int4* v4 = (const int4*)verts;
        int4 a = ntload_i4(&v4[3 * t + 0]);
        int4 b = ntload_i4(&v4[3 * t + 1]);
        int4 c = ntload_i4(&v4[3 * t + 2]);
        int w0 = vox_of(a.x, a.y, a.z);
        int w1 = vox_of(a.w, b.x, b.y);
        int w2 = vox_of(b.z, b.w, c.x);
        int w3 = vox_of(c.y, c.z, c.w);
        ((int4*)vox)[t] = make_int4(w0, w1, w2, w3);
        int r0 = atomicAdd(&counts[w0], 1);
        int r1 = atomicAdd(&counts[w1], 1);
        int r2 = atomicAdd(&counts[w2], 1);
        int r3 = atomicAdd(&counts[w3], 1);
        ((int4*)rank)[t] = make_int4(r0, r1, r2, r3);
    } else {
        for (int p = p0; p < n; p++) {
            int w = vox_of(verts[3 * p], verts[3 * p + 1], verts[3 * p + 2]);
            vox[p]  = w;
            rank[p] = atomicAdd(&counts[w], 1);
        }
    }
}

// ---- k2a: per-1024-chunk sums (256 chunks) ------------------------------
__global__ void __launch_bounds__(256)
k_bsum(const int* __restrict__ counts, int* __restrict__ bsum) {
    int b = blockIdx.x;            // 0..255
    int t = threadIdx.x;           // 0..255
    int4 c = ((const int4*)counts)[b * 256 + t];
    int s = c.x + c.y + c.z + c.w;
    #pragma unroll
    for (int off = 32; off; off >>= 1) s += __shfl_down(s, off);
    __shared__ int ws[4];
    int lane = t & 63, wid = t >> 6;
    if (lane == 0) ws[wid] = s;
    __syncthreads();
    if (t == 0) bsum[b] = ws[0] + ws[1] + ws[2] + ws[3];
}

// ---- k2b: exclusive scan of the 256 chunk sums (single block) ----------
__global__ void __launch_bounds__(256) k_scan2(int* __restrict__ bsum) {
    int t = threadIdx.x;
    int v = bsum[t];
    int lane = t & 63;
    int wid  = t >> 6;    // 0..3
    int incl = v;
    #pragma unroll
    for (int off = 1; off < 64; off <<= 1) {
        int u = __shfl_up(incl, off);
        if (lane >= off) incl += u;
    }
    __shared__ int ws[4];
    if (lane == 63) ws[wid] = incl;
    __syncthreads();
    int base = 0;
    for (int i = 0; i < wid; i++) base += ws[i];
    bsum[t] = base + incl - v;                // exclusive scan result
}

// ---- k2c: local scan + chunk base -> gstart[N_VOX+1] -------------------
__global__ void __launch_bounds__(1024)
k_scanfinal(const int* __restrict__ counts, const int* __restrict__ bsum,
            int* __restrict__ gstart) {
    int g = blockIdx.x * 1024 + threadIdx.x;
    int v = counts[g];
    int lane = threadIdx.x & 63;
    int wid  = threadIdx.x >> 6;      // 0..15

    int incl = v;
    #pragma unroll
    for (int off = 1; off < 64; off <<= 1) {
        int u = __shfl_up(incl, off);
        if (lane >= off) incl += u;
    }
    __shared__ int wsum[16];
    if (lane == 63) wsum[wid] = incl;
    __syncthreads();
    if (wid == 0) {
        int s  = (lane < 16) ? wsum[lane] : 0;
        int si = s;
        #pragma unroll
        for (int off = 1; off < 16; off <<= 1) {
            int u = __shfl_up(si, off);
            if (lane >= off) si += u;
        }
        if (lane < 16) wsum[lane] = si - s;   // exclusive wave base
    }
    __syncthreads();

    int start = bsum[blockIdx.x] + wsum[wid] + incl - v;
    gstart[g] = start;
    if (g == N_VOX - 1) gstart[N_VOX] = start + v;   // total sentinel
}

// ---- k3: scatter point indices — NO atomics (rank precomputed) ---------
__global__ void k_scatter_idx(const int* __restrict__ vox,
                              const int* __restrict__ rank,
                              const int* __restrict__ gstart,
                              int* __restrict__ sorted_idx, int n) {
    int t  = blockIdx.x * blockDim.x + threadIdx.x;
    int p0 = t * 4;
    if (p0 >= n) return;

    if (p0 + 4 <= n) {
        int4 w = ((const int4*)vox)[t];
        int4 r = ((const int4*)rank)[t];
        sorted_idx[gstart[w.x] + r.x] = p0 + 0;
        sorted_idx[gstart[w.y] + r.y] = p0 + 1;
        sorted_idx[gstart[w.z] + r.z] = p0 + 2;
        sorted_idx[gstart[w.w] + r.w] = p0 + 3;
    } else {
        for (int p = p0; p < n; p++)
            sorted_idx[gstart[vox[p]] + rank[p]] = p;
    }
}

// ---- k4: gather max — 16 voxels/block, indices staged in LDS -----------
#define VPB 16          // voxels per 256-thread block
#define IDX_CAP 2048    // LDS slots for the block's sorted_idx slice

__global__ void __launch_bounds__(256)
k_gather(const int* __restrict__ sorted_idx,
         const int* __restrict__ gstart,
         const float4* __restrict__ feats4,   // [N, 16] float4
         float4* __restrict__ out4) {         // [N_VOX, 16] float4
    __shared__ int sst[VPB + 1];
    __shared__ int sidx[IDX_CAP];

    int vox0 = blockIdx.x * VPB;
    if (threadIdx.x < VPB + 1) sst[threadIdx.x] = gstart[vox0 + threadIdx.x];
    __syncthreads();

    int bstart = sst[0];
    int span   = sst[VPB] - bstart;
    bool fits  = (span <= IDX_CAP);
    if (fits) {
        for (int i = threadIdx.x; i < span; i += 256)
            sidx[i] = sorted_idx[bstart + i];
    }
    __syncthreads();

    int g   = threadIdx.x >> 4;       // voxel within block 0..15
    int sub = threadIdx.x & 15;       // channel quad
    int s0  = sst[g];
    int cnt = sst[g + 1] - s0;
    float4* outp = &out4[(size_t)(vox0 + g) * 16 + sub];

    if (cnt == 0) {
        ntstore4(outp, make_float4(0.f, 0.f, 0.f, 0.f));
        return;
    }

    int off = s0 - bstart;
    float4 a0 = make_float4(-INFINITY, -INFINITY, -INFINITY, -INFINITY);
    float4 a1 = a0, a2 = a0, a3 = a0;

    for (int j = 0; j < cnt; j += 4) {
        int j1 = min(j + 1, cnt - 1);
        int j2 = min(j + 2, cnt - 1);
        int j3 = min(j + 3, cnt - 1);
        int p0, p1, p2, p3;
        if (fits) {
            p0 = sidx[off + j];  p1 = sidx[off + j1];
            p2 = sidx[off + j2]; p3 = sidx[off + j3];
        } else {
            p0 = sorted_idx[s0 + j];  p1 = sorted_idx[s0 + j1];
            p2 = sorted_idx[s0 + j2]; p3 = sorted_idx[s0 + j3];
        }
        float4 f0 = ntload4(&feats4[(size_t)p0 * 16 + sub]);
        float4 f1 = ntload4(&feats4[(size_t)p1 * 16 + sub]);
        float4 f2 = ntload4(&feats4[(size_t)p2 * 16 + sub]);
        float4 f3 = ntload4(&feats4[(size_t)p3 * 16 + sub]);
        a0 = max4(a0, f0);
        a1 = max4(a1, f1);
        a2 = max4(a2, f2);
        a3 = max4(a3, f3);
    }
    ntstore4(outp, max4(max4(a0, a1), max4(a2, a3)));
}

// ============================================================================
extern "C" void kernel_launch(void* const* d_in, const int* in_sizes, int n_in,
                              void* d_out, int out_size, void* d_ws, size_t ws_size,
                              hipStream_t stream) {
    const int*   verts = (const int*)d_in[0];    // [N,3] int32
    const float* feats = (const float*)d_in[1];  // [N,64] fp32
    float*       out   = (float*)d_out;          // [N_VOX*64] fp32

    const int n_pts = in_sizes[0] / 3;           // 1,000,000

    char* w = (char*)d_ws;
    int*  vox        = (int*)w;              w += (size_t)n_pts * 4;
    int*  rank       = (int*)w;              w += (size_t)n_pts * 4;
    int*  sorted_idx = (int*)w;              w += (size_t)n_pts * 4;
    int*  counts     = (int*)w;              w += (size_t)N_VOX * 4;
    int*  gstart     = (int*)w;              w += (size_t)(N_VOX + 16) * 4;
    int*  bsum       = (int*)w;

    hipMemsetAsync(counts, 0, (size_t)N_VOX * 4, stream);

    {   // histogram + voxel ids + in-voxel ranks (4 points/thread)
        const int block = 256;
        const int nthr  = (n_pts + 3) / 4;
        const int grid  = (nthr + block - 1) / block;
        k_hist<<<grid, block, 0, stream>>>(verts, vox, rank, counts, n_pts);
    }
    // hierarchical exclusive scan -> gstart[N_VOX+1]
    k_bsum<<<256, 256, 0, stream>>>(counts, bsum);
    k_scan2<<<1, 256, 0, stream>>>(bsum);
    k_scanfinal<<<N_VOX / 1024, 1024, 0, stream>>>(counts, bsum, gstart);

    {   // scatter indices, atomic-free (4 points/thread)
        const int block = 256;
        const int nthr  = (n_pts + 3) / 4;
        const int grid  = (nthr + block - 1) / block;
        k_scatter_idx<<<grid, block, 0, stream>>>(vox, rank, gstart,
                                                  sorted_idx, n_pts);
    }
    {   // gather max: 16 voxels per block, LDS-staged indices
        const int block = 256;
        const int grid  = N_VOX / VPB;     // 16384
        k_gather<<<grid, block, 0, stream>>>(sorted_idx, gstart,
                                             (const float4*)feats, (float4*)out);
    }
}